// Round 3
// baseline (287.491 us; speedup 1.0000x reference)
//
#include <hip/hip_runtime.h>

using u16 = unsigned short;
typedef __attribute__((ext_vector_type(8))) short bf16x8;  // guide-verified frag type
typedef __attribute__((ext_vector_type(4))) float f32x4;

constexpr int Bc = 2, Sc = 2048, Dc = 1024, Hc = 16;
constexpr int Mc = Bc * Sc;  // 4096
constexpr int N3 = 3 * Dc;   // 3072

__device__ __forceinline__ u16 f2bf(float f) {
  unsigned u = __float_as_uint(f);
  u += 0x7fffu + ((u >> 16) & 1u);  // RNE
  return (u16)(u >> 16);
}

__device__ __forceinline__ void gload16(const void* g, void* l) {
  __builtin_amdgcn_global_load_lds(
      (const __attribute__((address_space(1))) void*)g,
      (__attribute__((address_space(3))) void*)l, 16, 0, 0);
}

// element offset in a [rows][64]-bf16 tile (128 B rows, 8x 16B slots),
// slot XOR-swizzled by (row&7) — same involution on write-src and read.
__device__ __forceinline__ int swz(int row, int slot) {
  return row * 64 + ((slot ^ (row & 7)) << 3);
}

// ---------------------------------------------------------------------------
// LayerNorm: fp32 in -> bf16 out. One block per row.
// ---------------------------------------------------------------------------
__global__ __launch_bounds__(256) void ln_kernel(
    const float* __restrict__ x, const float* __restrict__ gamma,
    const float* __restrict__ beta, u16* __restrict__ xn) {
  __shared__ float sred[8];
  const int row = blockIdx.x, tid = threadIdx.x;
  const float4 a = ((const float4*)(x + (size_t)row * Dc))[tid];
  float s = a.x + a.y + a.z + a.w;
  float ss = a.x * a.x + a.y * a.y + a.z * a.z + a.w * a.w;
#pragma unroll
  for (int off = 32; off; off >>= 1) {
    s += __shfl_xor(s, off, 64);
    ss += __shfl_xor(ss, off, 64);
  }
  const int wid = tid >> 6, lane = tid & 63;
  if (lane == 0) { sred[wid] = s; sred[4 + wid] = ss; }
  __syncthreads();
  s = sred[0] + sred[1] + sred[2] + sred[3];
  ss = sred[4] + sred[5] + sred[6] + sred[7];
  const float mean = s * (1.0f / Dc);
  const float rstd = rsqrtf(ss * (1.0f / Dc) - mean * mean + 1e-5f);
  const float4 g = ((const float4*)gamma)[tid];
  const float4 b = ((const float4*)beta)[tid];
  ushort4 o;
  o.x = f2bf((a.x - mean) * rstd * g.x + b.x);
  o.y = f2bf((a.y - mean) * rstd * g.y + b.y);
  o.z = f2bf((a.z - mean) * rstd * g.z + b.z);
  o.w = f2bf((a.w - mean) * rstd * g.w + b.w);
  *(ushort4*)(xn + (size_t)row * Dc + tid * 4) = o;
}

// ---------------------------------------------------------------------------
// Convert + transpose: W fp32 [K][N] -> WT bf16 [N][K]. 32x32 tiles.
// ---------------------------------------------------------------------------
__global__ __launch_bounds__(256) void convertT(
    const float* __restrict__ W, u16* __restrict__ WT, int K, int N) {
  __shared__ float t[32][33];
  const int k0 = blockIdx.y * 32, n0 = blockIdx.x * 32;
  const int tid = threadIdx.x;
  const int r = tid >> 3, c4 = (tid & 7) << 2;
  const float4 v = *(const float4*)(W + (size_t)(k0 + r) * N + n0 + c4);
  t[r][c4 + 0] = v.x; t[r][c4 + 1] = v.y; t[r][c4 + 2] = v.z; t[r][c4 + 3] = v.w;
  __syncthreads();
  ushort4 o;
  o.x = f2bf(t[c4 + 0][r]); o.y = f2bf(t[c4 + 1][r]);
  o.z = f2bf(t[c4 + 2][r]); o.w = f2bf(t[c4 + 3][r]);
  *(ushort4*)(WT + (size_t)(n0 + r) * K + k0 + c4) = o;
}

// ---------------------------------------------------------------------------
// QKV GEMM (bf16 MFMA): xn[4096][1024] @ wqkvT[3072][1024]^T + bias.
// 128x128 tile, BK=64, 4 waves (2x2), wave tile 64x64.
// Epilogue scatters: Q(scaled 0.125)->[bh][s][hd], K->[bh][s][hd], V^T->[bh][hd][s]
// ---------------------------------------------------------------------------
__global__ __launch_bounds__(256) void gemm_qkv_kernel(
    const u16* __restrict__ A, const u16* __restrict__ BT,
    const float* __restrict__ bias, u16* __restrict__ Qb,
    u16* __restrict__ Kb, u16* __restrict__ VbT) {
  __shared__ __align__(16) u16 Al[128 * 64];
  __shared__ __align__(16) u16 Bl[128 * 64];
  const int tid = threadIdx.x, wv = tid >> 6, ln = tid & 63;
  const int bm = blockIdx.y * 128, bn = blockIdx.x * 128;
  const int wr = (wv >> 1) * 64, wc = (wv & 1) * 64;

  f32x4 acc[4][4];
#pragma unroll
  for (int i = 0; i < 4; i++)
#pragma unroll
    for (int j = 0; j < 4; j++) acc[i][j] = f32x4{0.f, 0.f, 0.f, 0.f};

  for (int k0 = 0; k0 < Dc; k0 += 64) {
    __syncthreads();
#pragma unroll
    for (int c = 0; c < 4; c++) {
      const int ci = wv + c * 4;              // chunk 0..15 (1 KB each)
      const int i = ci * 64 + ln;             // 0..1023 (16B units)
      const int row = i >> 3, slot = i & 7;
      const size_t go = (size_t)row * Dc + k0 + ((slot ^ (row & 7)) << 3);
      gload16(A + (size_t)bm * Dc + go, &Al[ci * 512]);
      gload16(BT + (size_t)bn * Dc + go, &Bl[ci * 512]);
    }
    __syncthreads();
#pragma unroll
    for (int ks = 0; ks < 2; ks++) {
      bf16x8 af[4], bfr[4];
#pragma unroll
      for (int m = 0; m < 4; m++)
        af[m] = *(const bf16x8*)&Al[swz(wr + m * 16 + (ln & 15), ks * 4 + (ln >> 4))];
#pragma unroll
      for (int n = 0; n < 4; n++)
        bfr[n] = *(const bf16x8*)&Bl[swz(wc + n * 16 + (ln & 15), ks * 4 + (ln >> 4))];
#pragma unroll
      for (int m = 0; m < 4; m++)
#pragma unroll
        for (int n = 0; n < 4; n++)
          acc[m][n] = __builtin_amdgcn_mfma_f32_16x16x32_bf16(af[m], bfr[n], acc[m][n], 0, 0, 0);
    }
  }

  const int fq = ln >> 4, fr = ln & 15;
#pragma unroll
  for (int mi = 0; mi < 4; mi++) {
    const int row = bm + wr + mi * 16 + fq * 4;  // + reg
    const int b = row >> 11, sl = row & 2047;
#pragma unroll
    for (int ni = 0; ni < 4; ni++) {
      const int col = bn + wc + ni * 16 + fr;
      const int which = col >> 10, h = (col >> 6) & 15, hd = col & 63;
      const int bh = b * Hc + h;
      const float bs = bias[col];
      if (which == 0) {
#pragma unroll
        for (int r = 0; r < 4; r++)
          Qb[((size_t)bh * Sc + sl + r) * 64 + hd] = f2bf((acc[mi][ni][r] + bs) * 0.125f);
      } else if (which == 1) {
#pragma unroll
        for (int r = 0; r < 4; r++)
          Kb[((size_t)bh * Sc + sl + r) * 64 + hd] = f2bf(acc[mi][ni][r] + bs);
      } else {
        ushort4 st;
        st.x = f2bf(acc[mi][ni][0] + bs); st.y = f2bf(acc[mi][ni][1] + bs);
        st.z = f2bf(acc[mi][ni][2] + bs); st.w = f2bf(acc[mi][ni][3] + bs);
        *(ushort4*)&VbT[((size_t)bh * 64 + hd) * Sc + sl] = st;
      }
    }
  }
}

// ---------------------------------------------------------------------------
// Flash attention, bf16 MFMA. Block = 4 waves; Q-tile 64 rows (16/wave);
// K/V tiles 64 keys staged via global_load_lds (pre-swizzled source).
// ---------------------------------------------------------------------------
__global__ __launch_bounds__(256) void attn_kernel(
    const u16* __restrict__ Qb, const u16* __restrict__ Kb,
    const u16* __restrict__ VbT, u16* __restrict__ ctx) {
  __shared__ __align__(16) u16 Ks[64 * 64];
  __shared__ __align__(16) u16 Vs[64 * 64];   // V^T: [hd][key]
  __shared__ __align__(16) u16 Pl[4][16 * 64];
  const int tid = threadIdx.x, wv = tid >> 6, ln = tid & 63;
  const int qt = blockIdx.x, bh = blockIdx.y;
  const int b = bh >> 4, h = bh & 15;
  const int q0 = qt * 64 + wv * 16;

  // Q fragments held in registers (already scaled by 0.125 in GEMM epilogue)
  bf16x8 qf[2];
  {
    const u16* Qrow = Qb + ((size_t)bh * Sc + q0 + (ln & 15)) * 64;
    qf[0] = *(const bf16x8*)(Qrow + ((ln >> 4) << 3));
    qf[1] = *(const bf16x8*)(Qrow + 32 + ((ln >> 4) << 3));
  }

  f32x4 O[4];
  float m_[4], l_[4];
#pragma unroll
  for (int f = 0; f < 4; f++) O[f] = f32x4{0.f, 0.f, 0.f, 0.f};
#pragma unroll
  for (int r = 0; r < 4; r++) { m_[r] = -1e30f; l_[r] = 0.f; }

  const u16* Kbase = Kb + (size_t)bh * Sc * 64;
  const u16* Vbase = VbT + (size_t)bh * 64 * Sc;
  u16* Pw = &Pl[wv][0];

  for (int kt = 0; kt < Sc / 64; kt++) {
    __syncthreads();
#pragma unroll
    for (int c = 0; c < 2; c++) {
      const int ci = wv + c * 4;            // chunk 0..7
      const int i = ci * 64 + ln;           // 0..511
      const int row = i >> 3, slot = i & 7;
      const int so = (slot ^ (row & 7)) << 3;
      gload16(Kbase + ((size_t)kt * 64 + row) * 64 + so, &Ks[ci * 512]);
      gload16(Vbase + (size_t)row * Sc + kt * 64 + so, &Vs[ci * 512]);
    }
    __syncthreads();

    // S = Q @ K^T  (C frag: key = f*16+(ln&15), q = (ln>>4)*4 + reg)
    f32x4 sf[4];
#pragma unroll
    for (int f = 0; f < 4; f++) {
      f32x4 s = f32x4{0.f, 0.f, 0.f, 0.f};
#pragma unroll
      for (int ks = 0; ks < 2; ks++) {
        bf16x8 kf = *(const bf16x8*)&Ks[swz(f * 16 + (ln & 15), ks * 4 + (ln >> 4))];
        s = __builtin_amdgcn_mfma_f32_16x16x32_bf16(qf[ks], kf, s, 0, 0, 0);
      }
      sf[f] = s;
    }

    // online softmax (q-row r lives on the 16 lanes sharing ln>>4)
    float al[4];
#pragma unroll
    for (int r = 0; r < 4; r++) {
      float v = fmaxf(fmaxf(sf[0][r], sf[1][r]), fmaxf(sf[2][r], sf[3][r]));
#pragma unroll
      for (int o = 1; o < 16; o <<= 1) v = fmaxf(v, __shfl_xor(v, o, 16));
      const float mn = fmaxf(m_[r], v);
      al[r] = __expf(m_[r] - mn);
      m_[r] = mn;
    }
    float rs[4] = {0.f, 0.f, 0.f, 0.f};
#pragma unroll
    for (int f = 0; f < 4; f++)
#pragma unroll
      for (int r = 0; r < 4; r++) {
        const float p = __expf(sf[f][r] - m_[r]);
        sf[f][r] = p;
        rs[r] += p;
      }
#pragma unroll
    for (int r = 0; r < 4; r++) {
#pragma unroll
      for (int o = 1; o < 16; o <<= 1) rs[r] += __shfl_xor(rs[r], o, 16);
      l_[r] = l_[r] * al[r] + rs[r];
    }
#pragma unroll
    for (int f = 0; f < 4; f++)
#pragma unroll
      for (int r = 0; r < 4; r++) O[f][r] *= al[r];

    // P -> per-wave LDS in A-fragment layout (swizzled rows of 128 B)
#pragma unroll
    for (int f = 0; f < 4; f++)
#pragma unroll
      for (int r = 0; r < 4; r++) {
        const int row = (ln >> 4) * 4 + r, key = f * 16 + (ln & 15);
        Pw[row * 64 + (key ^ ((row & 7) << 3))] = f2bf(sf[f][r]);
      }
    // cross-lane LDS handoff within the wave: pin program order (TBAA would
    // otherwise allow the vector reads below to hoist above the u16 stores)
    // and drain the DS pipe before the reads issue.
    asm volatile("s_waitcnt lgkmcnt(0)" ::: "memory");

    // O += P @ V
#pragma unroll
    for (int f = 0; f < 4; f++)
#pragma unroll
      for (int ks = 0; ks < 2; ks++) {
        bf16x8 pa = *(const bf16x8*)&Pw[swz(ln & 15, ks * 4 + (ln >> 4))];
        bf16x8 vb = *(const bf16x8*)&Vs[swz(f * 16 + (ln & 15), ks * 4 + (ln >> 4))];
        O[f] = __builtin_amdgcn_mfma_f32_16x16x32_bf16(pa, vb, O[f], 0, 0, 0);
      }
  }

#pragma unroll
  for (int r = 0; r < 4; r++) l_[r] = 1.0f / l_[r];
#pragma unroll
  for (int f = 0; f < 4; f++)
#pragma unroll
    for (int r = 0; r < 4; r++) {
      const int row = q0 + (ln >> 4) * 4 + r;
      ctx[((size_t)b * Sc + row) * Dc + h * 64 + f * 16 + (ln & 15)] =
          f2bf(O[f][r] * l_[r]);
    }
}

// ---------------------------------------------------------------------------
// Final fused dual GEMM: out = (ctx@w_out + b_out) * sigmoid(xn@w_gate + b_gate) + x
// 64x64 tile, BK=64, 4 waves (2x2), wave tile 32x32 per GEMM.
// ---------------------------------------------------------------------------
__global__ __launch_bounds__(256) void final_kernel(
    const u16* __restrict__ ctx, const u16* __restrict__ xn,
    const u16* __restrict__ woutT, const u16* __restrict__ wgateT,
    const float* __restrict__ b_out, const float* __restrict__ b_gate,
    const float* __restrict__ x, float* __restrict__ out) {
  __shared__ __align__(16) u16 A1[64 * 64], A2[64 * 64], B1[64 * 64], B2[64 * 64];
  const int tid = threadIdx.x, wv = tid >> 6, ln = tid & 63;
  const int bm = blockIdx.y * 64, bn = blockIdx.x * 64;
  const int wr = (wv >> 1) * 32, wc = (wv & 1) * 32;

  f32x4 ac1[2][2], ac2[2][2];
#pragma unroll
  for (int i = 0; i < 2; i++)
#pragma unroll
    for (int j = 0; j < 2; j++) {
      ac1[i][j] = f32x4{0.f, 0.f, 0.f, 0.f};
      ac2[i][j] = f32x4{0.f, 0.f, 0.f, 0.f};
    }

  for (int k0 = 0; k0 < Dc; k0 += 64) {
    __syncthreads();
#pragma unroll
    for (int c = 0; c < 2; c++) {
      const int ci = wv + c * 4;            // chunk 0..7 per tile
      const int i = ci * 64 + ln;
      const int row = i >> 3, slot = i & 7;
      const size_t go = (size_t)row * Dc + k0 + ((slot ^ (row & 7)) << 3);
      gload16(ctx + (size_t)bm * Dc + go, &A1[ci * 512]);
      gload16(xn + (size_t)bm * Dc + go, &A2[ci * 512]);
      gload16(woutT + (size_t)bn * Dc + go, &B1[ci * 512]);
      gload16(wgateT + (size_t)bn * Dc + go, &B2[ci * 512]);
    }
    __syncthreads();
#pragma unroll
    for (int ks = 0; ks < 2; ks++) {
      bf16x8 fa1[2], fa2[2], fb1[2], fb2[2];
#pragma unroll
      for (int m = 0; m < 2; m++) {
        const int off = swz(wr + m * 16 + (ln & 15), ks * 4 + (ln >> 4));
        fa1[m] = *(const bf16x8*)&A1[off];
        fa2[m] = *(const bf16x8*)&A2[off];
      }
#pragma unroll
      for (int n = 0; n < 2; n++) {
        const int off = swz(wc + n * 16 + (ln & 15), ks * 4 + (ln >> 4));
        fb1[n] = *(const bf16x8*)&B1[off];
        fb2[n] = *(const bf16x8*)&B2[off];
      }
#pragma unroll
      for (int m = 0; m < 2; m++)
#pragma unroll
        for (int n = 0; n < 2; n++) {
          ac1[m][n] = __builtin_amdgcn_mfma_f32_16x16x32_bf16(fa1[m], fb1[n], ac1[m][n], 0, 0, 0);
          ac2[m][n] = __builtin_amdgcn_mfma_f32_16x16x32_bf16(fa2[m], fb2[n], ac2[m][n], 0, 0, 0);
        }
    }
  }

  const int fq = ln >> 4, fr = ln & 15;
#pragma unroll
  for (int m = 0; m < 2; m++)
#pragma unroll
    for (int n = 0; n < 2; n++) {
      const int col = bn + wc + n * 16 + fr;
      const float bo = b_out[col], bg = b_gate[col];
#pragma unroll
      for (int r = 0; r < 4; r++) {
        const int row = bm + wr + m * 16 + fq * 4 + r;
        const float o = ac1[m][n][r] + bo;
        const float gv = ac2[m][n][r] + bg;
        const float sig = 1.0f / (1.0f + __expf(-gv));
        out[(size_t)row * Dc + col] = o * sig + x[(size_t)row * Dc + col];
      }
    }
}

// ---------------------------------------------------------------------------
extern "C" void kernel_launch(void* const* d_in, const int* in_sizes, int n_in,
                              void* d_out, int out_size, void* d_ws, size_t ws_size,
                              hipStream_t stream) {
  const float* x = (const float*)d_in[0];
  const float* gamma = (const float*)d_in[1];
  const float* beta = (const float*)d_in[2];
  const float* w_qkv = (const float*)d_in[3];
  const float* b_qkv = (const float*)d_in[4];
  const float* w_out = (const float*)d_in[5];
  const float* b_out = (const float*)d_in[6];
  const float* w_gate = (const float*)d_in[7];
  const float* b_gate = (const float*)d_in[8];
  float* out = (float*)d_out;

  u16* xn = (u16*)d_ws;                       // 4096*1024
  u16* wqkvT = xn + (size_t)Mc * Dc;          // 3072*1024
  u16* woutT = wqkvT + (size_t)N3 * Dc;       // 1024*1024
  u16* wgateT = woutT + (size_t)Dc * Dc;      // 1024*1024
  u16* Qb = wgateT + (size_t)Dc * Dc;         // 32*2048*64
  u16* Kb = Qb + (size_t)Bc * Hc * Sc * 64;
  u16* VbT = Kb + (size_t)Bc * Hc * Sc * 64;
  u16* ctxb = VbT + (size_t)Bc * Hc * Sc * 64;  // 4096*1024  (total 50 MB)

  ln_kernel<<<Mc, 256, 0, stream>>>(x, gamma, beta, xn);
  convertT<<<dim3(N3 / 32, Dc / 32), 256, 0, stream>>>(w_qkv, wqkvT, Dc, N3);
  convertT<<<dim3(Dc / 32, Dc / 32), 256, 0, stream>>>(w_out, woutT, Dc, Dc);
  convertT<<<dim3(Dc / 32, Dc / 32), 256, 0, stream>>>(w_gate, wgateT, Dc, Dc);
  gemm_qkv_kernel<<<dim3(N3 / 128, Mc / 128), 256, 0, stream>>>(
      xn, wqkvT, b_qkv, Qb, Kb, VbT);
  attn_kernel<<<dim3(Sc / 64, Bc * Hc), 256, 0, stream>>>(Qb, Kb, VbT, ctxb);
  final_kernel<<<dim3(Dc / 64, Mc / 64), 256, 0, stream>>>(
      ctxb, xn, woutT, wgateT, b_out, b_gate, x, out);
}

// Round 6
// 270.729 us; speedup vs baseline: 1.0619x; 1.0619x over previous
//
#include <hip/hip_runtime.h>

using u16 = unsigned short;
typedef __attribute__((ext_vector_type(8))) short bf16x8;  // guide-verified frag type
typedef __attribute__((ext_vector_type(4))) float f32x4;

constexpr int Bc = 2, Sc = 2048, Dc = 1024, Hc = 16;
constexpr int Mc = Bc * Sc;  // 4096
constexpr int N3 = 3 * Dc;   // 3072

__device__ __forceinline__ u16 f2bf(float f) {
  unsigned u = __float_as_uint(f);
  u += 0x7fffu + ((u >> 16) & 1u);  // RNE
  return (u16)(u >> 16);
}

__device__ __forceinline__ void gload16(const void* g, void* l) {
  __builtin_amdgcn_global_load_lds(
      (const __attribute__((address_space(1))) void*)g,
      (__attribute__((address_space(3))) void*)l, 16, 0, 0);
}

// element offset in a [rows][64]-bf16 tile (128 B rows, 8x 16B slots),
// slot XOR-swizzled by (row&7) — same involution on write-src and read.
__device__ __forceinline__ int swz(int row, int slot) {
  return row * 64 + ((slot ^ (row & 7)) << 3);
}

// T1 XCD-aware bijective block swizzle (requires nwg % 8 == 0).
// Consecutive remapped ids stay on one XCD and walk tiles contiguously.
__device__ __forceinline__ void xcd_swizzle(int& bx, int& by) {
  const int nwg = gridDim.x * gridDim.y;
  const int bid = by * gridDim.x + bx;
  const int s = (bid & 7) * (nwg >> 3) + (bid >> 3);
  bx = s % gridDim.x;
  by = s / gridDim.x;
}

// ---------------------------------------------------------------------------
// LayerNorm: fp32 in -> bf16 out. One block per row.
// ---------------------------------------------------------------------------
__global__ __launch_bounds__(256) void ln_kernel(
    const float* __restrict__ x, const float* __restrict__ gamma,
    const float* __restrict__ beta, u16* __restrict__ xn) {
  __shared__ float sred[8];
  const int row = blockIdx.x, tid = threadIdx.x;
  const float4 a = ((const float4*)(x + (size_t)row * Dc))[tid];
  float s = a.x + a.y + a.z + a.w;
  float ss = a.x * a.x + a.y * a.y + a.z * a.z + a.w * a.w;
#pragma unroll
  for (int off = 32; off; off >>= 1) {
    s += __shfl_xor(s, off, 64);
    ss += __shfl_xor(ss, off, 64);
  }
  const int wid = tid >> 6, lane = tid & 63;
  if (lane == 0) { sred[wid] = s; sred[4 + wid] = ss; }
  __syncthreads();
  s = sred[0] + sred[1] + sred[2] + sred[3];
  ss = sred[4] + sred[5] + sred[6] + sred[7];
  const float mean = s * (1.0f / Dc);
  const float rstd = rsqrtf(ss * (1.0f / Dc) - mean * mean + 1e-5f);
  const float4 g = ((const float4*)gamma)[tid];
  const float4 b = ((const float4*)beta)[tid];
  ushort4 o;
  o.x = f2bf((a.x - mean) * rstd * g.x + b.x);
  o.y = f2bf((a.y - mean) * rstd * g.y + b.y);
  o.z = f2bf((a.z - mean) * rstd * g.z + b.z);
  o.w = f2bf((a.w - mean) * rstd * g.w + b.w);
  *(ushort4*)(xn + (size_t)row * Dc + tid * 4) = o;
}

// ---------------------------------------------------------------------------
// Convert + transpose: W fp32 [K][N] -> WT bf16 [N][K]. 32x32 tiles.
// ---------------------------------------------------------------------------
__global__ __launch_bounds__(256) void convertT(
    const float* __restrict__ W, u16* __restrict__ WT, int K, int N) {
  __shared__ float t[32][33];
  const int k0 = blockIdx.y * 32, n0 = blockIdx.x * 32;
  const int tid = threadIdx.x;
  const int r = tid >> 3, c4 = (tid & 7) << 2;
  const float4 v = *(const float4*)(W + (size_t)(k0 + r) * N + n0 + c4);
  t[r][c4 + 0] = v.x; t[r][c4 + 1] = v.y; t[r][c4 + 2] = v.z; t[r][c4 + 3] = v.w;
  __syncthreads();
  ushort4 o;
  o.x = f2bf(t[c4 + 0][r]); o.y = f2bf(t[c4 + 1][r]);
  o.z = f2bf(t[c4 + 2][r]); o.w = f2bf(t[c4 + 3][r]);
  *(ushort4*)(WT + (size_t)(n0 + r) * K + k0 + c4) = o;
}

// ---------------------------------------------------------------------------
// QKV GEMM (bf16 MFMA): xn[4096][1024] @ wqkvT[3072][1024]^T + bias.
// 128x128 tile, BK=64, 4 waves (2x2), wave tile 64x64.
// Q is pre-scaled by 0.125*log2(e) so attention can use exp2.
// ---------------------------------------------------------------------------
__global__ __launch_bounds__(256) void gemm_qkv_kernel(
    const u16* __restrict__ A, const u16* __restrict__ BT,
    const float* __restrict__ bias, u16* __restrict__ Qb,
    u16* __restrict__ Kb, u16* __restrict__ VbT) {
  __shared__ __align__(16) u16 Al[128 * 64];
  __shared__ __align__(16) u16 Bl[128 * 64];
  const int tid = threadIdx.x, wv = tid >> 6, ln = tid & 63;
  int bxi = blockIdx.x, byi = blockIdx.y;
  xcd_swizzle(bxi, byi);
  const int bm = byi * 128, bn = bxi * 128;
  const int wr = (wv >> 1) * 64, wc = (wv & 1) * 64;

  f32x4 acc[4][4];
#pragma unroll
  for (int i = 0; i < 4; i++)
#pragma unroll
    for (int j = 0; j < 4; j++) acc[i][j] = f32x4{0.f, 0.f, 0.f, 0.f};

  for (int k0 = 0; k0 < Dc; k0 += 64) {
    __syncthreads();
#pragma unroll
    for (int c = 0; c < 4; c++) {
      const int ci = wv + c * 4;              // chunk 0..15 (1 KB each)
      const int i = ci * 64 + ln;             // 0..1023 (16B units)
      const int row = i >> 3, slot = i & 7;
      const size_t go = (size_t)row * Dc + k0 + ((slot ^ (row & 7)) << 3);
      gload16(A + (size_t)bm * Dc + go, &Al[ci * 512]);
      gload16(BT + (size_t)bn * Dc + go, &Bl[ci * 512]);
    }
    __syncthreads();
#pragma unroll
    for (int ks = 0; ks < 2; ks++) {
      bf16x8 af[4], bfr[4];
#pragma unroll
      for (int m = 0; m < 4; m++)
        af[m] = *(const bf16x8*)&Al[swz(wr + m * 16 + (ln & 15), ks * 4 + (ln >> 4))];
#pragma unroll
      for (int n = 0; n < 4; n++)
        bfr[n] = *(const bf16x8*)&Bl[swz(wc + n * 16 + (ln & 15), ks * 4 + (ln >> 4))];
#pragma unroll
      for (int m = 0; m < 4; m++)
#pragma unroll
        for (int n = 0; n < 4; n++)
          acc[m][n] = __builtin_amdgcn_mfma_f32_16x16x32_bf16(af[m], bfr[n], acc[m][n], 0, 0, 0);
    }
  }

  const int fq = ln >> 4, fr = ln & 15;
#pragma unroll
  for (int mi = 0; mi < 4; mi++) {
    const int row = bm + wr + mi * 16 + fq * 4;  // + reg
    const int b = row >> 11, sl = row & 2047;
#pragma unroll
    for (int ni = 0; ni < 4; ni++) {
      const int col = bn + wc + ni * 16 + fr;
      const int which = col >> 10, h = (col >> 6) & 15, hd = col & 63;
      const int bh = b * Hc + h;
      const float bs = bias[col];
      if (which == 0) {
        // 0.125 * log2(e): attention uses exp2 on these logits
#pragma unroll
        for (int r = 0; r < 4; r++)
          Qb[((size_t)bh * Sc + sl + r) * 64 + hd] =
              f2bf((acc[mi][ni][r] + bs) * 0.18033688011112042f);
      } else if (which == 1) {
#pragma unroll
        for (int r = 0; r < 4; r++)
          Kb[((size_t)bh * Sc + sl + r) * 64 + hd] = f2bf(acc[mi][ni][r] + bs);
      } else {
        ushort4 st;
        st.x = f2bf(acc[mi][ni][0] + bs); st.y = f2bf(acc[mi][ni][1] + bs);
        st.z = f2bf(acc[mi][ni][2] + bs); st.w = f2bf(acc[mi][ni][3] + bs);
        *(ushort4*)&VbT[((size_t)bh * 64 + hd) * Sc + sl] = st;
      }
    }
  }
}

// ---------------------------------------------------------------------------
// Flash attention, bf16 MFMA. Block = 2 waves x 32 q-rows; KVBLK=64;
// double-buffered K/V via global_load_lds (2-phase pipeline, counted drain);
// log2-domain online softmax with defer-max (no shuffles in steady state).
// ---------------------------------------------------------------------------
__global__ __launch_bounds__(128) void attn_kernel(
    const u16* __restrict__ Qb, const u16* __restrict__ Kb,
    const u16* __restrict__ VbT, u16* __restrict__ ctx) {
  __shared__ __align__(16) u16 Ks[2][64 * 64];
  __shared__ __align__(16) u16 Vs[2][64 * 64];   // V^T: [hd][key]
  __shared__ __align__(16) u16 Pl[2][32 * 64];   // per-wave P tile
  const int tid = threadIdx.x, wv = tid >> 6, ln = tid & 63;
  const int qt = blockIdx.x, bh = blockIdx.y;
  const int b = bh >> 4, h = bh & 15;
  const int q0 = qt * 64 + wv * 32;
  constexpr float THR = 11.5f;  // defer-max threshold (log2 domain, ~e^8)

  // Q fragments (pre-scaled by 0.125*log2e in GEMM epilogue)
  bf16x8 qf[2][2];
#pragma unroll
  for (int a = 0; a < 2; a++)
#pragma unroll
    for (int ks = 0; ks < 2; ks++)
      qf[a][ks] = *(const bf16x8*)(Qb + ((size_t)bh * Sc + q0 + a * 16 + (ln & 15)) * 64 +
                                   (ks * 4 + (ln >> 4)) * 8);

  f32x4 O[2][4];
  float m_[2][4], l_[2][4];
#pragma unroll
  for (int a = 0; a < 2; a++)
#pragma unroll
    for (int f = 0; f < 4; f++) O[a][f] = f32x4{0.f, 0.f, 0.f, 0.f};
#pragma unroll
  for (int a = 0; a < 2; a++)
#pragma unroll
    for (int r = 0; r < 4; r++) { m_[a][r] = -1e30f; l_[a][r] = 0.f; }

  const u16* Kbase = Kb + (size_t)bh * Sc * 64;
  const u16* Vbase = VbT + (size_t)bh * 64 * Sc;
  u16* Pw = &Pl[wv][0];

  // per-lane source offsets for the 4 staging chunks this wave owns
  int rk[4], rv[4];
#pragma unroll
  for (int c = 0; c < 4; c++) {
    const int ci = wv * 4 + c;
    const int i = ci * 64 + ln;
    const int row = i >> 3, slot = i & 7;
    const int so = (slot ^ (row & 7)) << 3;
    rk[c] = row * 64 + so;
    rv[c] = row * Sc + so;
  }

  auto stage = [&](int buf, int kt) {
#pragma unroll
    for (int c = 0; c < 4; c++) {
      const int ci = wv * 4 + c;
      gload16(Kbase + (size_t)kt * 4096 + rk[c], &Ks[buf][ci * 512]);
      gload16(Vbase + (size_t)kt * 64 + rv[c], &Vs[buf][ci * 512]);
    }
  };

  stage(0, 0);
  asm volatile("s_waitcnt vmcnt(0)" ::: "memory");
  __syncthreads();

  for (int kt = 0; kt < Sc / 64; kt++) {
    const int cur = kt & 1;
    if (kt + 1 < Sc / 64) stage(cur ^ 1, kt + 1);  // async prefetch

    // S = Q @ K^T  (C frag: key = f*16+(ln&15), q = a*16+(ln>>4)*4+reg)
    f32x4 sf[2][4];
#pragma unroll
    for (int a = 0; a < 2; a++)
#pragma unroll
      for (int f = 0; f < 4; f++) sf[a][f] = f32x4{0.f, 0.f, 0.f, 0.f};
    __builtin_amdgcn_s_setprio(1);
#pragma unroll
    for (int f = 0; f < 4; f++)
#pragma unroll
      for (int ks = 0; ks < 2; ks++) {
        const bf16x8 kf = *(const bf16x8*)&Ks[cur][swz(f * 16 + (ln & 15), ks * 4 + (ln >> 4))];
#pragma unroll
        for (int a = 0; a < 2; a++)
          sf[a][f] = __builtin_amdgcn_mfma_f32_16x16x32_bf16(qf[a][ks], kf, sf[a][f], 0, 0, 0);
      }
    __builtin_amdgcn_s_setprio(0);

    // defer-max online softmax (log2 domain). Steady state: no shuffles.
    float pm[2][4];
    bool need = false;
#pragma unroll
    for (int a = 0; a < 2; a++)
#pragma unroll
      for (int r = 0; r < 4; r++) {
        pm[a][r] = fmaxf(fmaxf(sf[a][0][r], sf[a][1][r]), fmaxf(sf[a][2][r], sf[a][3][r]));
        need |= pm[a][r] > m_[a][r] + THR;
      }
    if (__any(need)) {
#pragma unroll
      for (int a = 0; a < 2; a++)
#pragma unroll
        for (int r = 0; r < 4; r++) {
          float v = pm[a][r];
#pragma unroll
          for (int o = 1; o < 16; o <<= 1) v = fmaxf(v, __shfl_xor(v, o, 16));
          v = fmaxf(v, m_[a][r]);
          const float al = exp2f(m_[a][r] - v);
          m_[a][r] = v;
          l_[a][r] *= al;
#pragma unroll
          for (int f = 0; f < 4; f++) O[a][f][r] *= al;
        }
    }
#pragma unroll
    for (int a = 0; a < 2; a++)
#pragma unroll
      for (int f = 0; f < 4; f++)
#pragma unroll
        for (int r = 0; r < 4; r++) {
          const float p = exp2f(sf[a][f][r] - m_[a][r]);
          l_[a][r] += p;  // per-lane partial; reduced once at the end
          const int row = a * 16 + (ln >> 4) * 4 + r;
          const int key = f * 16 + (ln & 15);
          Pw[row * 64 + (key ^ ((row & 7) << 3))] = f2bf(p);
        }
    // order the u16 P-stores before the vector P-reads (cross-lane LDS handoff)
    asm volatile("s_waitcnt lgkmcnt(0)" ::: "memory");

    // O += P @ V
    __builtin_amdgcn_s_setprio(1);
#pragma unroll
    for (int ks = 0; ks < 2; ks++) {
      bf16x8 pa[2];
#pragma unroll
      for (int a = 0; a < 2; a++)
        pa[a] = *(const bf16x8*)&Pw[swz(a * 16 + (ln & 15), ks * 4 + (ln >> 4))];
#pragma unroll
      for (int f = 0; f < 4; f++) {
        const bf16x8 vb = *(const bf16x8*)&Vs[cur][swz(f * 16 + (ln & 15), ks * 4 + (ln >> 4))];
#pragma unroll
        for (int a = 0; a < 2; a++)
          O[a][f] = __builtin_amdgcn_mfma_f32_16x16x32_bf16(pa[a], vb, O[a][f], 0, 0, 0);
      }
    }
    __builtin_amdgcn_s_setprio(0);

    // drain prefetch, then all waves release this buffer
    asm volatile("s_waitcnt vmcnt(0)" ::: "memory");
    __syncthreads();
  }

  // final l reduction across the 16-lane group, then normalize + store
#pragma unroll
  for (int a = 0; a < 2; a++)
#pragma unroll
    for (int r = 0; r < 4; r++) {
      float v = l_[a][r];
#pragma unroll
      for (int o = 1; o < 16; o <<= 1) v += __shfl_xor(v, o, 16);
      l_[a][r] = 1.0f / v;
    }
#pragma unroll
  for (int a = 0; a < 2; a++)
#pragma unroll
    for (int f = 0; f < 4; f++)
#pragma unroll
      for (int r = 0; r < 4; r++) {
        const int row = q0 + a * 16 + (ln >> 4) * 4 + r;
        ctx[((size_t)b * Sc + row) * Dc + h * 64 + f * 16 + (ln & 15)] =
            f2bf(O[a][f][r] * l_[a][r]);
      }
}

// ---------------------------------------------------------------------------
// Final fused dual GEMM: out = (ctx@w_out + b_out) * sigmoid(xn@w_gate + b_gate) + x
// 128x64 tile, BK=64, 4 waves (2x2), wave tile 64x32 per GEMM.
// ---------------------------------------------------------------------------
__global__ __launch_bounds__(256) void final_kernel(
    const u16* __restrict__ ctx, const u16* __restrict__ xn,
    const u16* __restrict__ woutT, const u16* __restrict__ wgateT,
    const float* __restrict__ b_out, const float* __restrict__ b_gate,
    const float* __restrict__ x, float* __restrict__ out) {
  __shared__ __align__(16) u16 A1[128 * 64], A2[128 * 64];  // 16 KB each
  __shared__ __align__(16) u16 B1[64 * 64], B2[64 * 64];    // 8 KB each
  const int tid = threadIdx.x, wv = tid >> 6, ln = tid & 63;
  int bxi = blockIdx.x, byi = blockIdx.y;
  xcd_swizzle(bxi, byi);
  const int bm = byi * 128, bn = bxi * 64;
  const int wr = (wv >> 1) * 64, wc = (wv & 1) * 32;

  f32x4 ac1[4][2], ac2[4][2];
#pragma unroll
  for (int i = 0; i < 4; i++)
#pragma unroll
    for (int j = 0; j < 2; j++) {
      ac1[i][j] = f32x4{0.f, 0.f, 0.f, 0.f};
      ac2[i][j] = f32x4{0.f, 0.f, 0.f, 0.f};
    }

  for (int k0 = 0; k0 < Dc; k0 += 64) {
    __syncthreads();
    // A tiles: 128 rows -> 16 chunks, 4 per wave (same pattern as gemm_qkv)
#pragma unroll
    for (int c = 0; c < 4; c++) {
      const int ci = wv + c * 4;
      const int i = ci * 64 + ln;
      const int row = i >> 3, slot = i & 7;
      const size_t go = (size_t)row * Dc + k0 + ((slot ^ (row & 7)) << 3);
      gload16(ctx + (size_t)bm * Dc + go, &A1[ci * 512]);
      gload16(xn + (size_t)bm * Dc + go, &A2[ci * 512]);
    }
    // B tiles: 64 rows -> 8 chunks, 2 per wave
#pragma unroll
    for (int c = 0; c < 2; c++) {
      const int ci = wv + c * 4;
      const int i = ci * 64 + ln;
      const int row = i >> 3, slot = i & 7;
      const size_t go = (size_t)row * Dc + k0 + ((slot ^ (row & 7)) << 3);
      gload16(woutT + (size_t)bn * Dc + go, &B1[ci * 512]);
      gload16(wgateT + (size_t)bn * Dc + go, &B2[ci * 512]);
    }
    __syncthreads();
#pragma unroll
    for (int ks = 0; ks < 2; ks++) {
      bf16x8 fa1[4], fa2[4], fb1[2], fb2[2];
#pragma unroll
      for (int m = 0; m < 4; m++) {
        const int off = swz(wr + m * 16 + (ln & 15), ks * 4 + (ln >> 4));
        fa1[m] = *(const bf16x8*)&A1[off];
        fa2[m] = *(const bf16x8*)&A2[off];
      }
#pragma unroll
      for (int n = 0; n < 2; n++) {
        const int off = swz(wc + n * 16 + (ln & 15), ks * 4 + (ln >> 4));
        fb1[n] = *(const bf16x8*)&B1[off];
        fb2[n] = *(const bf16x8*)&B2[off];
      }
#pragma unroll
      for (int m = 0; m < 4; m++)
#pragma unroll
        for (int n = 0; n < 2; n++) {
          ac1[m][n] = __builtin_amdgcn_mfma_f32_16x16x32_bf16(fa1[m], fb1[n], ac1[m][n], 0, 0, 0);
          ac2[m][n] = __builtin_amdgcn_mfma_f32_16x16x32_bf16(fa2[m], fb2[n], ac2[m][n], 0, 0, 0);
        }
    }
  }

  const int fq = ln >> 4, fr = ln & 15;
#pragma unroll
  for (int m = 0; m < 4; m++)
#pragma unroll
    for (int n = 0; n < 2; n++) {
      const int col = bn + wc + n * 16 + fr;
      const float bo = b_out[col], bg = b_gate[col];
#pragma unroll
      for (int r = 0; r < 4; r++) {
        const int row = bm + wr + m * 16 + fq * 4 + r;
        const float o = ac1[m][n][r] + bo;
        const float gv = ac2[m][n][r] + bg;
        const float sig = 1.0f / (1.0f + __expf(-gv));
        out[(size_t)row * Dc + col] = o * sig + x[(size_t)row * Dc + col];
      }
    }
}

// ---------------------------------------------------------------------------
extern "C" void kernel_launch(void* const* d_in, const int* in_sizes, int n_in,
                              void* d_out, int out_size, void* d_ws, size_t ws_size,
                              hipStream_t stream) {
  const float* x = (const float*)d_in[0];
  const float* gamma = (const float*)d_in[1];
  const float* beta = (const float*)d_in[2];
  const float* w_qkv = (const float*)d_in[3];
  const float* b_qkv = (const float*)d_in[4];
  const float* w_out = (const float*)d_in[5];
  const float* b_out = (const float*)d_in[6];
  const float* w_gate = (const float*)d_in[7];
  const float* b_gate = (const float*)d_in[8];
  float* out = (float*)d_out;

  u16* xn = (u16*)d_ws;                       // 4096*1024
  u16* wqkvT = xn + (size_t)Mc * Dc;          // 3072*1024
  u16* woutT = wqkvT + (size_t)N3 * Dc;       // 1024*1024
  u16* wgateT = woutT + (size_t)Dc * Dc;      // 1024*1024
  u16* Qb = wgateT + (size_t)Dc * Dc;         // 32*2048*64
  u16* Kb = Qb + (size_t)Bc * Hc * Sc * 64;
  u16* VbT = Kb + (size_t)Bc * Hc * Sc * 64;
  u16* ctxb = VbT + (size_t)Bc * Hc * Sc * 64;  // 4096*1024  (total 50 MB)

  ln_kernel<<<Mc, 256, 0, stream>>>(x, gamma, beta, xn);
  convertT<<<dim3(N3 / 32, Dc / 32), 256, 0, stream>>>(w_qkv, wqkvT, Dc, N3);
  convertT<<<dim3(Dc / 32, Dc / 32), 256, 0, stream>>>(w_out, woutT, Dc, Dc);
  convertT<<<dim3(Dc / 32, Dc / 32), 256, 0, stream>>>(w_gate, wgateT, Dc, Dc);
  gemm_qkv_kernel<<<dim3(N3 / 128, Mc / 128), 256, 0, stream>>>(
      xn, wqkvT, b_qkv, Qb, Kb, VbT);
  attn_kernel<<<dim3(Sc / 64, Bc * Hc), 128, 0, stream>>>(Qb, Kb, VbT, ctxb);
  final_kernel<<<dim3(Dc / 64, Mc / 128), 256, 0, stream>>>(
      ctxb, xn, woutT, wgateT, b_out, b_gate, x, out);
}

// Round 7
// 251.548 us; speedup vs baseline: 1.1429x; 1.0763x over previous
//
#include <hip/hip_runtime.h>

using u16 = unsigned short;
typedef __attribute__((ext_vector_type(8))) short bf16x8;  // guide-verified frag type
typedef __attribute__((ext_vector_type(4))) float f32x4;

constexpr int Bc = 2, Sc = 2048, Dc = 1024, Hc = 16;
constexpr int Mc = Bc * Sc;  // 4096
constexpr int N3 = 3 * Dc;   // 3072

// pack 4 floats -> 4 bf16 (RNE) via 2x v_cvt_pk_bf16_f32 (guide T12 recipe)
__device__ __forceinline__ ushort4 pk4(float a, float b, float c, float d) {
  union { uint2 u; ushort4 s; } r;
  asm("v_cvt_pk_bf16_f32 %0, %1, %2" : "=v"(r.u.x) : "v"(a), "v"(b));
  asm("v_cvt_pk_bf16_f32 %0, %1, %2" : "=v"(r.u.y) : "v"(c), "v"(d));
  return r.s;
}

__device__ __forceinline__ void gload16(const void* g, void* l) {
  __builtin_amdgcn_global_load_lds(
      (const __attribute__((address_space(1))) void*)g,
      (__attribute__((address_space(3))) void*)l, 16, 0, 0);
}

// element offset in a [rows][64]-bf16 tile (128 B rows, 8x 16B slots),
// slot XOR-swizzled by (row&7) — same involution on write-src and read.
__device__ __forceinline__ int swz(int row, int slot) {
  return row * 64 + ((slot ^ (row & 7)) << 3);
}

// T1 XCD-aware bijective block swizzle (requires nwg % 8 == 0).
__device__ __forceinline__ void xcd_swizzle(int& bx, int& by) {
  const int nwg = gridDim.x * gridDim.y;
  const int bid = by * gridDim.x + bx;
  const int s = (bid & 7) * (nwg >> 3) + (bid >> 3);
  bx = s % gridDim.x;
  by = s / gridDim.x;
}

// ---------------------------------------------------------------------------
// LayerNorm: fp32 in -> bf16 out. One block per row.
// ---------------------------------------------------------------------------
__global__ __launch_bounds__(256) void ln_kernel(
    const float* __restrict__ x, const float* __restrict__ gamma,
    const float* __restrict__ beta, u16* __restrict__ xn) {
  __shared__ float sred[8];
  const int row = blockIdx.x, tid = threadIdx.x;
  const float4 a = ((const float4*)(x + (size_t)row * Dc))[tid];
  float s = a.x + a.y + a.z + a.w;
  float ss = a.x * a.x + a.y * a.y + a.z * a.z + a.w * a.w;
#pragma unroll
  for (int off = 32; off; off >>= 1) {
    s += __shfl_xor(s, off, 64);
    ss += __shfl_xor(ss, off, 64);
  }
  const int wid = tid >> 6, lane = tid & 63;
  if (lane == 0) { sred[wid] = s; sred[4 + wid] = ss; }
  __syncthreads();
  s = sred[0] + sred[1] + sred[2] + sred[3];
  ss = sred[4] + sred[5] + sred[6] + sred[7];
  const float mean = s * (1.0f / Dc);
  const float rstd = rsqrtf(ss * (1.0f / Dc) - mean * mean + 1e-5f);
  const float4 g = ((const float4*)gamma)[tid];
  const float4 b = ((const float4*)beta)[tid];
  *(ushort4*)(xn + (size_t)row * Dc + tid * 4) =
      pk4((a.x - mean) * rstd * g.x + b.x, (a.y - mean) * rstd * g.y + b.y,
          (a.z - mean) * rstd * g.z + b.z, (a.w - mean) * rstd * g.w + b.w);
}

// ---------------------------------------------------------------------------
// Convert + transpose: W fp32 [K][N] -> WT bf16 [N][K]. 32x32 tiles.
// ---------------------------------------------------------------------------
__global__ __launch_bounds__(256) void convertT(
    const float* __restrict__ W, u16* __restrict__ WT, int K, int N) {
  __shared__ float t[32][33];
  const int k0 = blockIdx.y * 32, n0 = blockIdx.x * 32;
  const int tid = threadIdx.x;
  const int r = tid >> 3, c4 = (tid & 7) << 2;
  const float4 v = *(const float4*)(W + (size_t)(k0 + r) * N + n0 + c4);
  t[r][c4 + 0] = v.x; t[r][c4 + 1] = v.y; t[r][c4 + 2] = v.z; t[r][c4 + 3] = v.w;
  __syncthreads();
  *(ushort4*)(WT + (size_t)(n0 + r) * K + k0 + c4) =
      pk4(t[c4 + 0][r], t[c4 + 1][r], t[c4 + 2][r], t[c4 + 3][r]);
}

// ---------------------------------------------------------------------------
// QKV GEMM (bf16 MFMA): xn[4096][1024] @ wqkvT[3072][1024]^T + bias.
// 128x128 tile, BK=64, 4 waves (2x2), wave tile 64x64.
// Q is pre-scaled by 0.125*log2(e) so attention can use exp2.
// ---------------------------------------------------------------------------
__global__ __launch_bounds__(256) void gemm_qkv_kernel(
    const u16* __restrict__ A, const u16* __restrict__ BT,
    const float* __restrict__ bias, u16* __restrict__ Qb,
    u16* __restrict__ Kb, u16* __restrict__ VbT) {
  __shared__ __align__(16) u16 Al[128 * 64];
  __shared__ __align__(16) u16 Bl[128 * 64];
  const int tid = threadIdx.x, wv = tid >> 6, ln = tid & 63;
  int bxi = blockIdx.x, byi = blockIdx.y;
  xcd_swizzle(bxi, byi);
  const int bm = byi * 128, bn = bxi * 128;
  const int wr = (wv >> 1) * 64, wc = (wv & 1) * 64;

  f32x4 acc[4][4];
#pragma unroll
  for (int i = 0; i < 4; i++)
#pragma unroll
    for (int j = 0; j < 4; j++) acc[i][j] = f32x4{0.f, 0.f, 0.f, 0.f};

  for (int k0 = 0; k0 < Dc; k0 += 64) {
    __syncthreads();
#pragma unroll
    for (int c = 0; c < 4; c++) {
      const int ci = wv + c * 4;              // chunk 0..15 (1 KB each)
      const int i = ci * 64 + ln;             // 0..1023 (16B units)
      const int row = i >> 3, slot = i & 7;
      const size_t go = (size_t)row * Dc + k0 + ((slot ^ (row & 7)) << 3);
      gload16(A + (size_t)bm * Dc + go, &Al[ci * 512]);
      gload16(BT + (size_t)bn * Dc + go, &Bl[ci * 512]);
    }
    __syncthreads();
#pragma unroll
    for (int ks = 0; ks < 2; ks++) {
      bf16x8 af[4], bfr[4];
#pragma unroll
      for (int m = 0; m < 4; m++)
        af[m] = *(const bf16x8*)&Al[swz(wr + m * 16 + (ln & 15), ks * 4 + (ln >> 4))];
#pragma unroll
      for (int n = 0; n < 4; n++)
        bfr[n] = *(const bf16x8*)&Bl[swz(wc + n * 16 + (ln & 15), ks * 4 + (ln >> 4))];
#pragma unroll
      for (int m = 0; m < 4; m++)
#pragma unroll
        for (int n = 0; n < 4; n++)
          acc[m][n] = __builtin_amdgcn_mfma_f32_16x16x32_bf16(af[m], bfr[n], acc[m][n], 0, 0, 0);
    }
  }

  const int fq = ln >> 4, fr = ln & 15;
#pragma unroll
  for (int mi = 0; mi < 4; mi++) {
    const int row = bm + wr + mi * 16 + fq * 4;  // + reg
    const int b = row >> 11, sl = row & 2047;
#pragma unroll
    for (int ni = 0; ni < 4; ni++) {
      const int col = bn + wc + ni * 16 + fr;
      const int which = col >> 10, h = (col >> 6) & 15, hd = col & 63;
      const int bh = b * Hc + h;
      const float bs = bias[col];
      if (which == 0) {
        // 0.125 * log2(e): attention uses exp2 on these logits
        constexpr float SC = 0.18033688011112042f;
        const ushort4 s = pk4((acc[mi][ni][0] + bs) * SC, (acc[mi][ni][1] + bs) * SC,
                              (acc[mi][ni][2] + bs) * SC, (acc[mi][ni][3] + bs) * SC);
        u16* p = &Qb[((size_t)bh * Sc + sl) * 64 + hd];
        p[0] = s.x; p[64] = s.y; p[128] = s.z; p[192] = s.w;
      } else if (which == 1) {
        const ushort4 s = pk4(acc[mi][ni][0] + bs, acc[mi][ni][1] + bs,
                              acc[mi][ni][2] + bs, acc[mi][ni][3] + bs);
        u16* p = &Kb[((size_t)bh * Sc + sl) * 64 + hd];
        p[0] = s.x; p[64] = s.y; p[128] = s.z; p[192] = s.w;
      } else {
        *(ushort4*)&VbT[((size_t)bh * 64 + hd) * Sc + sl] =
            pk4(acc[mi][ni][0] + bs, acc[mi][ni][1] + bs,
                acc[mi][ni][2] + bs, acc[mi][ni][3] + bs);
      }
    }
  }
}

// ---------------------------------------------------------------------------
// Flash attention, bf16 MFMA. Block = 2 waves x 32 q-rows; KVBLK=64;
// double-buffered K/V via global_load_lds; SWAPPED QK^T (mfma(K,Q)) so each
// lane owns 4 consecutive keys -> cvt_pk pairs + ds_write_b64 P-stores.
// log2-domain defer-max softmax, per-lane m/l state.
// ---------------------------------------------------------------------------
__global__ __launch_bounds__(128) void attn_kernel(
    const u16* __restrict__ Qb, const u16* __restrict__ Kb,
    const u16* __restrict__ VbT, u16* __restrict__ ctx) {
  __shared__ __align__(16) u16 Ks[2][64 * 64];
  __shared__ __align__(16) u16 Vs[2][64 * 64];   // V^T: [hd][key]
  __shared__ __align__(16) u16 Pl[2][32 * 64];   // per-wave P tile [q][key]
  const int tid = threadIdx.x, wv = tid >> 6, ln = tid & 63;
  const int g = ln >> 4, q = ln & 15;
  const int qt = blockIdx.x, bh = blockIdx.y;
  const int b = bh >> 4, h = bh & 15;
  const int q0 = qt * 64 + wv * 32;
  constexpr float THR = 11.5f;  // defer-max threshold (log2 domain ~ e^8)
  const f32x4 ZZ = {0.f, 0.f, 0.f, 0.f};

  // Q fragments (pre-scaled by 0.125*log2e); valid as B-operand (same layout)
  bf16x8 qf[2][2];
#pragma unroll
  for (int a = 0; a < 2; a++)
#pragma unroll
    for (int ks = 0; ks < 2; ks++)
      qf[a][ks] = *(const bf16x8*)(Qb + ((size_t)bh * Sc + q0 + a * 16 + q) * 64 +
                                   (ks * 4 + g) * 8);

  f32x4 O[2][4];
#pragma unroll
  for (int a = 0; a < 2; a++)
#pragma unroll
    for (int f = 0; f < 4; f++) O[a][f] = ZZ;
  float m_[2] = {-1e30f, -1e30f}, l_[2] = {0.f, 0.f};

  const u16* Kbase = Kb + (size_t)bh * Sc * 64;
  const u16* Vbase = VbT + (size_t)bh * 64 * Sc;
  u16* Pw = &Pl[wv][0];

  // P-store offsets (u16 units), loop-invariant: row = a*16+q, keys f*16+g*4..+3
  int pofs[2][4];
#pragma unroll
  for (int a = 0; a < 2; a++)
#pragma unroll
    for (int f = 0; f < 4; f++) {
      const int row = a * 16 + q;
      const int slot = 2 * f + (g >> 1);
      pofs[a][f] = row * 64 + ((slot ^ (q & 7)) << 3) + (g & 1) * 4;
    }

  // per-lane staging source offsets (4 chunks per wave)
  int rk[4], rv[4];
#pragma unroll
  for (int c = 0; c < 4; c++) {
    const int ci = wv * 4 + c;
    const int i = ci * 64 + ln;
    const int row = i >> 3, slot = i & 7;
    const int so = (slot ^ (row & 7)) << 3;
    rk[c] = row * 64 + so;
    rv[c] = row * Sc + so;
  }

  auto stage = [&](int buf, int kt) {
#pragma unroll
    for (int c = 0; c < 4; c++) {
      const int ci = wv * 4 + c;
      gload16(Kbase + (size_t)kt * 4096 + rk[c], &Ks[buf][ci * 512]);
      gload16(Vbase + (size_t)kt * 64 + rv[c], &Vs[buf][ci * 512]);
    }
  };

  stage(0, 0);
  asm volatile("s_waitcnt vmcnt(0)" ::: "memory");
  __syncthreads();

  for (int kt = 0; kt < Sc / 64; kt++) {
    const int cur = kt & 1;
    if (kt + 1 < Sc / 64) stage(cur ^ 1, kt + 1);  // async prefetch

    // S^T = K @ Q  (C frag: key = f*16 + g*4 + reg, q-col = a*16 + q)
    f32x4 sf[2][4];
    __builtin_amdgcn_s_setprio(1);
#pragma unroll
    for (int f = 0; f < 4; f++) {
      const bf16x8 kf0 = *(const bf16x8*)&Ks[cur][swz(f * 16 + q, g)];
      const bf16x8 kf1 = *(const bf16x8*)&Ks[cur][swz(f * 16 + q, 4 + g)];
#pragma unroll
      for (int a = 0; a < 2; a++) {
        f32x4 t = __builtin_amdgcn_mfma_f32_16x16x32_bf16(kf0, qf[a][0], ZZ, 0, 0, 0);
        sf[a][f] = __builtin_amdgcn_mfma_f32_16x16x32_bf16(kf1, qf[a][1], t, 0, 0, 0);
      }
    }
    __builtin_amdgcn_s_setprio(0);

    // defer-max online softmax, per-lane state (one q per lane per a)
    float pm[2];
    bool need = false;
#pragma unroll
    for (int a = 0; a < 2; a++) {
      float v = fmaxf(fmaxf(sf[a][0][0], sf[a][0][1]), fmaxf(sf[a][0][2], sf[a][0][3]));
#pragma unroll
      for (int f = 1; f < 4; f++) {
        v = fmaxf(v, fmaxf(fmaxf(sf[a][f][0], sf[a][f][1]), fmaxf(sf[a][f][2], sf[a][f][3])));
      }
      pm[a] = v;
      need |= pm[a] > m_[a] + THR;
    }
    if (__any(need)) {
#pragma unroll
      for (int a = 0; a < 2; a++) {
        float v = pm[a];
        v = fmaxf(v, __shfl_xor(v, 16));
        v = fmaxf(v, __shfl_xor(v, 32));
        v = fmaxf(v, m_[a]);
        const float al = exp2f(m_[a] - v);
        m_[a] = v;
        l_[a] *= al;
#pragma unroll
        for (int r = 0; r < 4; r++) {
          const float alo = __shfl(al, g * 4 + r);  // O row q' = a*16+g*4+r
#pragma unroll
          for (int f = 0; f < 4; f++) O[a][f][r] *= alo;
        }
      }
    }
    // p = exp2(s - m), pack pairs, one b64 store per (a,f)
#pragma unroll
    for (int a = 0; a < 2; a++) {
      float linc = 0.f;
#pragma unroll
      for (int f = 0; f < 4; f++) {
        const float p0 = exp2f(sf[a][f][0] - m_[a]);
        const float p1 = exp2f(sf[a][f][1] - m_[a]);
        const float p2 = exp2f(sf[a][f][2] - m_[a]);
        const float p3 = exp2f(sf[a][f][3] - m_[a]);
        linc += (p0 + p1) + (p2 + p3);
        uint2 pk;
        asm("v_cvt_pk_bf16_f32 %0, %1, %2" : "=v"(pk.x) : "v"(p0), "v"(p1));
        asm("v_cvt_pk_bf16_f32 %0, %1, %2" : "=v"(pk.y) : "v"(p2), "v"(p3));
        *(uint2*)&Pw[pofs[a][f]] = pk;
      }
      l_[a] += linc;
    }
    // order P-stores before the vector P-reads (cross-lane LDS handoff)
    asm volatile("s_waitcnt lgkmcnt(0)" ::: "memory");

    // O += P @ V
    __builtin_amdgcn_s_setprio(1);
#pragma unroll
    for (int ks = 0; ks < 2; ks++) {
      bf16x8 pa[2];
#pragma unroll
      for (int a = 0; a < 2; a++)
        pa[a] = *(const bf16x8*)&Pw[swz(a * 16 + q, ks * 4 + g)];
#pragma unroll
      for (int f = 0; f < 4; f++) {
        const bf16x8 vb = *(const bf16x8*)&Vs[cur][swz(f * 16 + q, ks * 4 + g)];
#pragma unroll
        for (int a = 0; a < 2; a++)
          O[a][f] = __builtin_amdgcn_mfma_f32_16x16x32_bf16(pa[a], vb, O[a][f], 0, 0, 0);
      }
    }
    __builtin_amdgcn_s_setprio(0);

    // drain prefetch, then all waves release this buffer
    asm volatile("s_waitcnt vmcnt(0)" ::: "memory");
    __syncthreads();
  }

  // final: full l per q (reduce group copies), fetch per-O-row inverse
#pragma unroll
  for (int a = 0; a < 2; a++) {
    l_[a] += __shfl_xor(l_[a], 16);
    l_[a] += __shfl_xor(l_[a], 32);
  }
  float linv[2][4];
#pragma unroll
  for (int a = 0; a < 2; a++)
#pragma unroll
    for (int r = 0; r < 4; r++)
      linv[a][r] = 1.0f / __shfl(l_[a], g * 4 + r);

#pragma unroll
  for (int a = 0; a < 2; a++)
#pragma unroll
    for (int f = 0; f < 4; f++) {
      const ushort4 s = pk4(O[a][f][0] * linv[a][0], O[a][f][1] * linv[a][1],
                            O[a][f][2] * linv[a][2], O[a][f][3] * linv[a][3]);
      u16* p = ctx + ((size_t)b * Sc + q0 + a * 16 + g * 4) * Dc + h * 64 + f * 16 + q;
      p[0] = s.x; p[Dc] = s.y; p[2 * Dc] = s.z; p[3 * Dc] = s.w;
    }
}

// ---------------------------------------------------------------------------
// Final fused dual GEMM: out = (ctx@w_out + b_out) * sigmoid(xn@w_gate + b_gate) + x
// 128x64 tile, BK=64, 4 waves (2x2), wave tile 64x32 per GEMM.
// ---------------------------------------------------------------------------
__global__ __launch_bounds__(256) void final_kernel(
    const u16* __restrict__ ctx, const u16* __restrict__ xn,
    const u16* __restrict__ woutT, const u16* __restrict__ wgateT,
    const float* __restrict__ b_out, const float* __restrict__ b_gate,
    const float* __restrict__ x, float* __restrict__ out) {
  __shared__ __align__(16) u16 A1[128 * 64], A2[128 * 64];  // 16 KB each
  __shared__ __align__(16) u16 B1[64 * 64], B2[64 * 64];    // 8 KB each
  const int tid = threadIdx.x, wv = tid >> 6, ln = tid & 63;
  int bxi = blockIdx.x, byi = blockIdx.y;
  xcd_swizzle(bxi, byi);
  const int bm = byi * 128, bn = bxi * 64;
  const int wr = (wv >> 1) * 64, wc = (wv & 1) * 32;

  f32x4 ac1[4][2], ac2[4][2];
#pragma unroll
  for (int i = 0; i < 4; i++)
#pragma unroll
    for (int j = 0; j < 2; j++) {
      ac1[i][j] = f32x4{0.f, 0.f, 0.f, 0.f};
      ac2[i][j] = f32x4{0.f, 0.f, 0.f, 0.f};
    }

  for (int k0 = 0; k0 < Dc; k0 += 64) {
    __syncthreads();
    // A tiles: 128 rows -> 16 chunks, 4 per wave
#pragma unroll
    for (int c = 0; c < 4; c++) {
      const int ci = wv + c * 4;
      const int i = ci * 64 + ln;
      const int row = i >> 3, slot = i & 7;
      const size_t go = (size_t)row * Dc + k0 + ((slot ^ (row & 7)) << 3);
      gload16(ctx + (size_t)bm * Dc + go, &A1[ci * 512]);
      gload16(xn + (size_t)bm * Dc + go, &A2[ci * 512]);
    }
    // B tiles: 64 rows -> 8 chunks, 2 per wave
#pragma unroll
    for (int c = 0; c < 2; c++) {
      const int ci = wv + c * 4;
      const int i = ci * 64 + ln;
      const int row = i >> 3, slot = i & 7;
      const size_t go = (size_t)row * Dc + k0 + ((slot ^ (row & 7)) << 3);
      gload16(woutT + (size_t)bn * Dc + go, &B1[ci * 512]);
      gload16(wgateT + (size_t)bn * Dc + go, &B2[ci * 512]);
    }
    __syncthreads();
#pragma unroll
    for (int ks = 0; ks < 2; ks++) {
      bf16x8 fa1[4], fa2[4], fb1[2], fb2[2];
#pragma unroll
      for (int m = 0; m < 4; m++) {
        const int off = swz(wr + m * 16 + (ln & 15), ks * 4 + (ln >> 4));
        fa1[m] = *(const bf16x8*)&A1[off];
        fa2[m] = *(const bf16x8*)&A2[off];
      }
#pragma unroll
      for (int n = 0; n < 2; n++) {
        const int off = swz(wc + n * 16 + (ln & 15), ks * 4 + (ln >> 4));
        fb1[n] = *(const bf16x8*)&B1[off];
        fb2[n] = *(const bf16x8*)&B2[off];
      }
#pragma unroll
      for (int m = 0; m < 4; m++)
#pragma unroll
        for (int n = 0; n < 2; n++) {
          ac1[m][n] = __builtin_amdgcn_mfma_f32_16x16x32_bf16(fa1[m], fb1[n], ac1[m][n], 0, 0, 0);
          ac2[m][n] = __builtin_amdgcn_mfma_f32_16x16x32_bf16(fa2[m], fb2[n], ac2[m][n], 0, 0, 0);
        }
    }
  }

  const int fq = ln >> 4, fr = ln & 15;
#pragma unroll
  for (int m = 0; m < 4; m++)
#pragma unroll
    for (int n = 0; n < 2; n++) {
      const int col = bn + wc + n * 16 + fr;
      const float bo = b_out[col], bg = b_gate[col];
#pragma unroll
      for (int r = 0; r < 4; r++) {
        const int row = bm + wr + m * 16 + fq * 4 + r;
        const float o = ac1[m][n][r] + bo;
        const float gv = ac2[m][n][r] + bg;
        const float sig = 1.0f / (1.0f + __expf(-gv));
        out[(size_t)row * Dc + col] = o * sig + x[(size_t)row * Dc + col];
      }
    }
}

// ---------------------------------------------------------------------------
extern "C" void kernel_launch(void* const* d_in, const int* in_sizes, int n_in,
                              void* d_out, int out_size, void* d_ws, size_t ws_size,
                              hipStream_t stream) {
  const float* x = (const float*)d_in[0];
  const float* gamma = (const float*)d_in[1];
  const float* beta = (const float*)d_in[2];
  const float* w_qkv = (const float*)d_in[3];
  const float* b_qkv = (const float*)d_in[4];
  const float* w_out = (const float*)d_in[5];
  const float* b_out = (const float*)d_in[6];
  const float* w_gate = (const float*)d_in[7];
  const float* b_gate = (const float*)d_in[8];
  float* out = (float*)d_out;

  u16* xn = (u16*)d_ws;                       // 4096*1024
  u16* wqkvT = xn + (size_t)Mc * Dc;          // 3072*1024
  u16* woutT = wqkvT + (size_t)N3 * Dc;       // 1024*1024
  u16* wgateT = woutT + (size_t)Dc * Dc;      // 1024*1024
  u16* Qb = wgateT + (size_t)Dc * Dc;         // 32*2048*64
  u16* Kb = Qb + (size_t)Bc * Hc * Sc * 64;
  u16* VbT = Kb + (size_t)Bc * Hc * Sc * 64;
  u16* ctxb = VbT + (size_t)Bc * Hc * Sc * 64;  // 4096*1024  (total 50 MB)

  ln_kernel<<<Mc, 256, 0, stream>>>(x, gamma, beta, xn);
  convertT<<<dim3(N3 / 32, Dc / 32), 256, 0, stream>>>(w_qkv, wqkvT, Dc, N3);
  convertT<<<dim3(Dc / 32, Dc / 32), 256, 0, stream>>>(w_out, woutT, Dc, Dc);
  convertT<<<dim3(Dc / 32, Dc / 32), 256, 0, stream>>>(w_gate, wgateT, Dc, Dc);
  gemm_qkv_kernel<<<dim3(N3 / 128, Mc / 128), 256, 0, stream>>>(
      xn, wqkvT, b_qkv, Qb, Kb, VbT);
  attn_kernel<<<dim3(Sc / 64, Bc * Hc), 128, 0, stream>>>(Qb, Kb, VbT, ctxb);
  final_kernel<<<dim3(Dc / 64, Mc / 128), 256, 0, stream>>>(
      ctxb, xn, woutT, wgateT, b_out, b_gate, x, out);
}

// Round 8
// 241.690 us; speedup vs baseline: 1.1895x; 1.0408x over previous
//
#include <hip/hip_runtime.h>

using u16 = unsigned short;
typedef __attribute__((ext_vector_type(8))) short bf16x8;  // guide-verified frag type
typedef __attribute__((ext_vector_type(4))) float f32x4;

constexpr int Bc = 2, Sc = 2048, Dc = 1024, Hc = 16;
constexpr int Mc = Bc * Sc;  // 4096
constexpr int N3 = 3 * Dc;   // 3072

// pack 4 floats -> 4 bf16 (RNE) via 2x v_cvt_pk_bf16_f32 (guide T12 recipe)
__device__ __forceinline__ ushort4 pk4(float a, float b, float c, float d) {
  union { uint2 u; ushort4 s; } r;
  asm("v_cvt_pk_bf16_f32 %0, %1, %2" : "=v"(r.u.x) : "v"(a), "v"(b));
  asm("v_cvt_pk_bf16_f32 %0, %1, %2" : "=v"(r.u.y) : "v"(c), "v"(d));
  return r.s;
}

__device__ __forceinline__ void gload16(const void* g, void* l) {
  __builtin_amdgcn_global_load_lds(
      (const __attribute__((address_space(1))) void*)g,
      (__attribute__((address_space(3))) void*)l, 16, 0, 0);
}

// element offset in a [rows][64]-bf16 tile (128 B rows, 8x 16B slots),
// slot XOR-swizzled by (row&7) — same involution on write-src and read.
__device__ __forceinline__ int swz(int row, int slot) {
  return row * 64 + ((slot ^ (row & 7)) << 3);
}

// T1 XCD-aware bijective block swizzle (requires nwg % 8 == 0).
__device__ __forceinline__ void xcd_swizzle(int& bx, int& by) {
  const int nwg = gridDim.x * gridDim.y;
  const int bid = by * gridDim.x + bx;
  const int s = (bid & 7) * (nwg >> 3) + (bid >> 3);
  bx = s % gridDim.x;
  by = s / gridDim.x;
}

// ---------------------------------------------------------------------------
// LayerNorm: fp32 in -> bf16 out. One block per row.
// ---------------------------------------------------------------------------
__global__ __launch_bounds__(256) void ln_kernel(
    const float* __restrict__ x, const float* __restrict__ gamma,
    const float* __restrict__ beta, u16* __restrict__ xn) {
  __shared__ float sred[8];
  const int row = blockIdx.x, tid = threadIdx.x;
  const float4 a = ((const float4*)(x + (size_t)row * Dc))[tid];
  float s = a.x + a.y + a.z + a.w;
  float ss = a.x * a.x + a.y * a.y + a.z * a.z + a.w * a.w;
#pragma unroll
  for (int off = 32; off; off >>= 1) {
    s += __shfl_xor(s, off, 64);
    ss += __shfl_xor(ss, off, 64);
  }
  const int wid = tid >> 6, lane = tid & 63;
  if (lane == 0) { sred[wid] = s; sred[4 + wid] = ss; }
  __syncthreads();
  s = sred[0] + sred[1] + sred[2] + sred[3];
  ss = sred[4] + sred[5] + sred[6] + sred[7];
  const float mean = s * (1.0f / Dc);
  const float rstd = rsqrtf(ss * (1.0f / Dc) - mean * mean + 1e-5f);
  const float4 g = ((const float4*)gamma)[tid];
  const float4 b = ((const float4*)beta)[tid];
  *(ushort4*)(xn + (size_t)row * Dc + tid * 4) =
      pk4((a.x - mean) * rstd * g.x + b.x, (a.y - mean) * rstd * g.y + b.y,
          (a.z - mean) * rstd * g.z + b.z, (a.w - mean) * rstd * g.w + b.w);
}

// ---------------------------------------------------------------------------
// Convert + transpose: W fp32 [K][N] -> WT bf16 [N][K]. 32x32 tiles.
// ---------------------------------------------------------------------------
__global__ __launch_bounds__(256) void convertT(
    const float* __restrict__ W, u16* __restrict__ WT, int K, int N) {
  __shared__ float t[32][33];
  const int k0 = blockIdx.y * 32, n0 = blockIdx.x * 32;
  const int tid = threadIdx.x;
  const int r = tid >> 3, c4 = (tid & 7) << 2;
  const float4 v = *(const float4*)(W + (size_t)(k0 + r) * N + n0 + c4);
  t[r][c4 + 0] = v.x; t[r][c4 + 1] = v.y; t[r][c4 + 2] = v.z; t[r][c4 + 3] = v.w;
  __syncthreads();
  *(ushort4*)(WT + (size_t)(n0 + r) * K + k0 + c4) =
      pk4(t[c4 + 0][r], t[c4 + 1][r], t[c4 + 2][r], t[c4 + 3][r]);
}

// ---------------------------------------------------------------------------
// QKV GEMM (bf16 MFMA): xn[4096][1024] @ wqkvT[3072][1024]^T + bias.
// 128x128 tile, BK=64, 4 waves (2x2), wave tile 64x64.
// Q is pre-scaled by 0.125*log2(e) so attention can use exp2.
// ---------------------------------------------------------------------------
__global__ __launch_bounds__(256) void gemm_qkv_kernel(
    const u16* __restrict__ A, const u16* __restrict__ BT,
    const float* __restrict__ bias, u16* __restrict__ Qb,
    u16* __restrict__ Kb, u16* __restrict__ VbT) {
  __shared__ __align__(16) u16 Al[128 * 64];
  __shared__ __align__(16) u16 Bl[128 * 64];
  const int tid = threadIdx.x, wv = tid >> 6, ln = tid & 63;
  int bxi = blockIdx.x, byi = blockIdx.y;
  xcd_swizzle(bxi, byi);
  const int bm = byi * 128, bn = bxi * 128;
  const int wr = (wv >> 1) * 64, wc = (wv & 1) * 64;

  f32x4 acc[4][4];
#pragma unroll
  for (int i = 0; i < 4; i++)
#pragma unroll
    for (int j = 0; j < 4; j++) acc[i][j] = f32x4{0.f, 0.f, 0.f, 0.f};

  for (int k0 = 0; k0 < Dc; k0 += 64) {
    __syncthreads();
#pragma unroll
    for (int c = 0; c < 4; c++) {
      const int ci = wv + c * 4;              // chunk 0..15 (1 KB each)
      const int i = ci * 64 + ln;             // 0..1023 (16B units)
      const int row = i >> 3, slot = i & 7;
      const size_t go = (size_t)row * Dc + k0 + ((slot ^ (row & 7)) << 3);
      gload16(A + (size_t)bm * Dc + go, &Al[ci * 512]);
      gload16(BT + (size_t)bn * Dc + go, &Bl[ci * 512]);
    }
    __syncthreads();
#pragma unroll
    for (int ks = 0; ks < 2; ks++) {
      bf16x8 af[4], bfr[4];
#pragma unroll
      for (int m = 0; m < 4; m++)
        af[m] = *(const bf16x8*)&Al[swz(wr + m * 16 + (ln & 15), ks * 4 + (ln >> 4))];
#pragma unroll
      for (int n = 0; n < 4; n++)
        bfr[n] = *(const bf16x8*)&Bl[swz(wc + n * 16 + (ln & 15), ks * 4 + (ln >> 4))];
#pragma unroll
      for (int m = 0; m < 4; m++)
#pragma unroll
        for (int n = 0; n < 4; n++)
          acc[m][n] = __builtin_amdgcn_mfma_f32_16x16x32_bf16(af[m], bfr[n], acc[m][n], 0, 0, 0);
    }
  }

  const int fq = ln >> 4, fr = ln & 15;
#pragma unroll
  for (int mi = 0; mi < 4; mi++) {
    const int row = bm + wr + mi * 16 + fq * 4;  // + reg
    const int b = row >> 11, sl = row & 2047;
#pragma unroll
    for (int ni = 0; ni < 4; ni++) {
      const int col = bn + wc + ni * 16 + fr;
      const int which = col >> 10, h = (col >> 6) & 15, hd = col & 63;
      const int bh = b * Hc + h;
      const float bs = bias[col];
      if (which == 0) {
        // 0.125 * log2(e): attention uses exp2 on these logits
        constexpr float SC = 0.18033688011112042f;
        const ushort4 s = pk4((acc[mi][ni][0] + bs) * SC, (acc[mi][ni][1] + bs) * SC,
                              (acc[mi][ni][2] + bs) * SC, (acc[mi][ni][3] + bs) * SC);
        u16* p = &Qb[((size_t)bh * Sc + sl) * 64 + hd];
        p[0] = s.x; p[64] = s.y; p[128] = s.z; p[192] = s.w;
      } else if (which == 1) {
        const ushort4 s = pk4(acc[mi][ni][0] + bs, acc[mi][ni][1] + bs,
                              acc[mi][ni][2] + bs, acc[mi][ni][3] + bs);
        u16* p = &Kb[((size_t)bh * Sc + sl) * 64 + hd];
        p[0] = s.x; p[64] = s.y; p[128] = s.z; p[192] = s.w;
      } else {
        *(ushort4*)&VbT[((size_t)bh * 64 + hd) * Sc + sl] =
            pk4(acc[mi][ni][0] + bs, acc[mi][ni][1] + bs,
                acc[mi][ni][2] + bs, acc[mi][ni][3] + bs);
      }
    }
  }
}

// ---------------------------------------------------------------------------
// Flash attention, bf16 MFMA. Block = 4 waves x 32 q-rows (128-row tile);
// one shared double-buffered K/V (LDS 48KB -> 3 blocks/CU, 12 waves/CU);
// swapped QK^T + cvt_pk P path; log2 defer-max softmax.
// Grid: flat 512, bh-locality XCD mapping (each XCD works 4 heads -> L2 reuse).
// ---------------------------------------------------------------------------
__global__ __launch_bounds__(256) void attn_kernel(
    const u16* __restrict__ Qb, const u16* __restrict__ Kb,
    const u16* __restrict__ VbT, u16* __restrict__ ctx) {
  __shared__ __align__(16) u16 Ks[2][64 * 64];
  __shared__ __align__(16) u16 Vs[2][64 * 64];   // V^T: [hd][key]
  __shared__ __align__(16) u16 Pl[4][32 * 64];   // per-wave P tile [q][key]
  const int tid = threadIdx.x, wv = tid >> 6, ln = tid & 63;
  const int g = ln >> 4, q = ln & 15;
  // bh-locality mapping: XCD (bid&7) covers heads 4*(bid&7)..+3 for all qt
  const int bid = blockIdx.x;
  const int idx = bid >> 3;
  const int bh = (bid & 7) * 4 + (idx & 3);
  const int qt = idx >> 2;
  const int b = bh >> 4, h = bh & 15;
  const int q0 = qt * 128 + wv * 32;
  constexpr float THR = 11.5f;  // defer-max threshold (log2 domain ~ e^8)
  const f32x4 ZZ = {0.f, 0.f, 0.f, 0.f};

  // Q fragments (pre-scaled by 0.125*log2e); valid as B-operand (same layout)
  bf16x8 qf[2][2];
#pragma unroll
  for (int a = 0; a < 2; a++)
#pragma unroll
    for (int ks = 0; ks < 2; ks++)
      qf[a][ks] = *(const bf16x8*)(Qb + ((size_t)bh * Sc + q0 + a * 16 + q) * 64 +
                                   (ks * 4 + g) * 8);

  f32x4 O[2][4];
#pragma unroll
  for (int a = 0; a < 2; a++)
#pragma unroll
    for (int f = 0; f < 4; f++) O[a][f] = ZZ;
  float m_[2] = {-1e30f, -1e30f}, l_[2] = {0.f, 0.f};

  const u16* Kbase = Kb + (size_t)bh * Sc * 64;
  const u16* Vbase = VbT + (size_t)bh * 64 * Sc;
  u16* Pw = &Pl[wv][0];

  // P-store offsets (u16 units), loop-invariant: row = a*16+q, keys f*16+g*4..+3
  int pofs[2][4];
#pragma unroll
  for (int a = 0; a < 2; a++)
#pragma unroll
    for (int f = 0; f < 4; f++) {
      const int row = a * 16 + q;
      const int slot = 2 * f + (g >> 1);
      pofs[a][f] = row * 64 + ((slot ^ (q & 7)) << 3) + (g & 1) * 4;
    }

  // per-lane staging source offsets (2 chunks per wave; 8 chunks of 1KB total)
  int rk[2], rv[2];
#pragma unroll
  for (int c = 0; c < 2; c++) {
    const int ci = wv * 2 + c;
    const int i = ci * 64 + ln;
    const int row = i >> 3, slot = i & 7;
    const int so = (slot ^ (row & 7)) << 3;
    rk[c] = row * 64 + so;
    rv[c] = row * Sc + so;
  }

  auto stage = [&](int buf, int kt) {
#pragma unroll
    for (int c = 0; c < 2; c++) {
      const int ci = wv * 2 + c;
      gload16(Kbase + (size_t)kt * 4096 + rk[c], &Ks[buf][ci * 512]);
      gload16(Vbase + (size_t)kt * 64 + rv[c], &Vs[buf][ci * 512]);
    }
  };

  stage(0, 0);
  asm volatile("s_waitcnt vmcnt(0)" ::: "memory");
  __syncthreads();

  for (int kt = 0; kt < Sc / 64; kt++) {
    const int cur = kt & 1;
    if (kt + 1 < Sc / 64) stage(cur ^ 1, kt + 1);  // async prefetch

    // S^T = K @ Q  (C frag: key = f*16 + g*4 + reg, q-col = a*16 + q)
    f32x4 sf[2][4];
    __builtin_amdgcn_s_setprio(1);
#pragma unroll
    for (int f = 0; f < 4; f++) {
      const bf16x8 kf0 = *(const bf16x8*)&Ks[cur][swz(f * 16 + q, g)];
      const bf16x8 kf1 = *(const bf16x8*)&Ks[cur][swz(f * 16 + q, 4 + g)];
#pragma unroll
      for (int a = 0; a < 2; a++) {
        f32x4 t = __builtin_amdgcn_mfma_f32_16x16x32_bf16(kf0, qf[a][0], ZZ, 0, 0, 0);
        sf[a][f] = __builtin_amdgcn_mfma_f32_16x16x32_bf16(kf1, qf[a][1], t, 0, 0, 0);
      }
    }
    __builtin_amdgcn_s_setprio(0);

    // defer-max online softmax, per-lane state (one q per lane per a)
    float pm[2];
    bool need = false;
#pragma unroll
    for (int a = 0; a < 2; a++) {
      float v = fmaxf(fmaxf(sf[a][0][0], sf[a][0][1]), fmaxf(sf[a][0][2], sf[a][0][3]));
#pragma unroll
      for (int f = 1; f < 4; f++) {
        v = fmaxf(v, fmaxf(fmaxf(sf[a][f][0], sf[a][f][1]), fmaxf(sf[a][f][2], sf[a][f][3])));
      }
      pm[a] = v;
      need |= pm[a] > m_[a] + THR;
    }
    if (__any(need)) {
#pragma unroll
      for (int a = 0; a < 2; a++) {
        float v = pm[a];
        v = fmaxf(v, __shfl_xor(v, 16));
        v = fmaxf(v, __shfl_xor(v, 32));
        v = fmaxf(v, m_[a]);
        const float al = exp2f(m_[a] - v);
        m_[a] = v;
        l_[a] *= al;
#pragma unroll
        for (int r = 0; r < 4; r++) {
          const float alo = __shfl(al, g * 4 + r);  // O row q' = a*16+g*4+r
#pragma unroll
          for (int f = 0; f < 4; f++) O[a][f][r] *= alo;
        }
      }
    }
    // p = exp2(s - m), pack pairs, one b64 store per (a,f)
#pragma unroll
    for (int a = 0; a < 2; a++) {
      float linc = 0.f;
#pragma unroll
      for (int f = 0; f < 4; f++) {
        const float p0 = exp2f(sf[a][f][0] - m_[a]);
        const float p1 = exp2f(sf[a][f][1] - m_[a]);
        const float p2 = exp2f(sf[a][f][2] - m_[a]);
        const float p3 = exp2f(sf[a][f][3] - m_[a]);
        linc += (p0 + p1) + (p2 + p3);
        uint2 pk;
        asm("v_cvt_pk_bf16_f32 %0, %1, %2" : "=v"(pk.x) : "v"(p0), "v"(p1));
        asm("v_cvt_pk_bf16_f32 %0, %1, %2" : "=v"(pk.y) : "v"(p2), "v"(p3));
        *(uint2*)&Pw[pofs[a][f]] = pk;
      }
      l_[a] += linc;
    }
    // order P-stores before the vector P-reads (cross-lane LDS handoff)
    asm volatile("s_waitcnt lgkmcnt(0)" ::: "memory");

    // O += P @ V
    __builtin_amdgcn_s_setprio(1);
#pragma unroll
    for (int ks = 0; ks < 2; ks++) {
      bf16x8 pa[2];
#pragma unroll
      for (int a = 0; a < 2; a++)
        pa[a] = *(const bf16x8*)&Pw[swz(a * 16 + q, ks * 4 + g)];
#pragma unroll
      for (int f = 0; f < 4; f++) {
        const bf16x8 vb = *(const bf16x8*)&Vs[cur][swz(f * 16 + q, ks * 4 + g)];
#pragma unroll
        for (int a = 0; a < 2; a++)
          O[a][f] = __builtin_amdgcn_mfma_f32_16x16x32_bf16(pa[a], vb, O[a][f], 0, 0, 0);
      }
    }
    __builtin_amdgcn_s_setprio(0);

    // drain prefetch, then all waves release this buffer
    asm volatile("s_waitcnt vmcnt(0)" ::: "memory");
    __syncthreads();
  }

  // final: full l per q (reduce group copies), fetch per-O-row inverse
#pragma unroll
  for (int a = 0; a < 2; a++) {
    l_[a] += __shfl_xor(l_[a], 16);
    l_[a] += __shfl_xor(l_[a], 32);
  }
  float linv[2][4];
#pragma unroll
  for (int a = 0; a < 2; a++)
#pragma unroll
    for (int r = 0; r < 4; r++)
      linv[a][r] = 1.0f / __shfl(l_[a], g * 4 + r);

#pragma unroll
  for (int a = 0; a < 2; a++)
#pragma unroll
    for (int f = 0; f < 4; f++) {
      const ushort4 s = pk4(O[a][f][0] * linv[a][0], O[a][f][1] * linv[a][1],
                            O[a][f][2] * linv[a][2], O[a][f][3] * linv[a][3]);
      u16* p = ctx + ((size_t)b * Sc + q0 + a * 16 + g * 4) * Dc + h * 64 + f * 16 + q;
      p[0] = s.x; p[Dc] = s.y; p[2 * Dc] = s.z; p[3 * Dc] = s.w;
    }
}

// ---------------------------------------------------------------------------
// Final fused dual GEMM: out = (ctx@w_out + b_out) * sigmoid(xn@w_gate + b_gate) + x
// 128x64 tile, BK=64, 4 waves (2x2), wave tile 64x32 per GEMM.
// ---------------------------------------------------------------------------
__global__ __launch_bounds__(256) void final_kernel(
    const u16* __restrict__ ctx, const u16* __restrict__ xn,
    const u16* __restrict__ woutT, const u16* __restrict__ wgateT,
    const float* __restrict__ b_out, const float* __restrict__ b_gate,
    const float* __restrict__ x, float* __restrict__ out) {
  __shared__ __align__(16) u16 A1[128 * 64], A2[128 * 64];  // 16 KB each
  __shared__ __align__(16) u16 B1[64 * 64], B2[64 * 64];    // 8 KB each
  const int tid = threadIdx.x, wv = tid >> 6, ln = tid & 63;
  int bxi = blockIdx.x, byi = blockIdx.y;
  xcd_swizzle(bxi, byi);
  const int bm = byi * 128, bn = bxi * 64;
  const int wr = (wv >> 1) * 64, wc = (wv & 1) * 32;

  f32x4 ac1[4][2], ac2[4][2];
#pragma unroll
  for (int i = 0; i < 4; i++)
#pragma unroll
    for (int j = 0; j < 2; j++) {
      ac1[i][j] = f32x4{0.f, 0.f, 0.f, 0.f};
      ac2[i][j] = f32x4{0.f, 0.f, 0.f, 0.f};
    }

  for (int k0 = 0; k0 < Dc; k0 += 64) {
    __syncthreads();
    // A tiles: 128 rows -> 16 chunks, 4 per wave
#pragma unroll
    for (int c = 0; c < 4; c++) {
      const int ci = wv + c * 4;
      const int i = ci * 64 + ln;
      const int row = i >> 3, slot = i & 7;
      const size_t go = (size_t)row * Dc + k0 + ((slot ^ (row & 7)) << 3);
      gload16(ctx + (size_t)bm * Dc + go, &A1[ci * 512]);
      gload16(xn + (size_t)bm * Dc + go, &A2[ci * 512]);
    }
    // B tiles: 64 rows -> 8 chunks, 2 per wave
#pragma unroll
    for (int c = 0; c < 2; c++) {
      const int ci = wv + c * 4;
      const int i = ci * 64 + ln;
      const int row = i >> 3, slot = i & 7;
      const size_t go = (size_t)row * Dc + k0 + ((slot ^ (row & 7)) << 3);
      gload16(woutT + (size_t)bn * Dc + go, &B1[ci * 512]);
      gload16(wgateT + (size_t)bn * Dc + go, &B2[ci * 512]);
    }
    __syncthreads();
#pragma unroll
    for (int ks = 0; ks < 2; ks++) {
      bf16x8 fa1[4], fa2[4], fb1[2], fb2[2];
#pragma unroll
      for (int m = 0; m < 4; m++) {
        const int off = swz(wr + m * 16 + (ln & 15), ks * 4 + (ln >> 4));
        fa1[m] = *(const bf16x8*)&A1[off];
        fa2[m] = *(const bf16x8*)&A2[off];
      }
#pragma unroll
      for (int n = 0; n < 2; n++) {
        const int off = swz(wc + n * 16 + (ln & 15), ks * 4 + (ln >> 4));
        fb1[n] = *(const bf16x8*)&B1[off];
        fb2[n] = *(const bf16x8*)&B2[off];
      }
#pragma unroll
      for (int m = 0; m < 4; m++)
#pragma unroll
        for (int n = 0; n < 2; n++) {
          ac1[m][n] = __builtin_amdgcn_mfma_f32_16x16x32_bf16(fa1[m], fb1[n], ac1[m][n], 0, 0, 0);
          ac2[m][n] = __builtin_amdgcn_mfma_f32_16x16x32_bf16(fa2[m], fb2[n], ac2[m][n], 0, 0, 0);
        }
    }
  }

  const int fq = ln >> 4, fr = ln & 15;
#pragma unroll
  for (int m = 0; m < 4; m++)
#pragma unroll
    for (int n = 0; n < 2; n++) {
      const int col = bn + wc + n * 16 + fr;
      const float bo = b_out[col], bg = b_gate[col];
#pragma unroll
      for (int r = 0; r < 4; r++) {
        const int row = bm + wr + m * 16 + fq * 4 + r;
        const float o = ac1[m][n][r] + bo;
        const float gv = ac2[m][n][r] + bg;
        const float sig = 1.0f / (1.0f + __expf(-gv));
        out[(size_t)row * Dc + col] = o * sig + x[(size_t)row * Dc + col];
      }
    }
}

// ---------------------------------------------------------------------------
extern "C" void kernel_launch(void* const* d_in, const int* in_sizes, int n_in,
                              void* d_out, int out_size, void* d_ws, size_t ws_size,
                              hipStream_t stream) {
  const float* x = (const float*)d_in[0];
  const float* gamma = (const float*)d_in[1];
  const float* beta = (const float*)d_in[2];
  const float* w_qkv = (const float*)d_in[3];
  const float* b_qkv = (const float*)d_in[4];
  const float* w_out = (const float*)d_in[5];
  const float* b_out = (const float*)d_in[6];
  const float* w_gate = (const float*)d_in[7];
  const float* b_gate = (const float*)d_in[8];
  float* out = (float*)d_out;

  u16* xn = (u16*)d_ws;                       // 4096*1024
  u16* wqkvT = xn + (size_t)Mc * Dc;          // 3072*1024
  u16* woutT = wqkvT + (size_t)N3 * Dc;       // 1024*1024
  u16* wgateT = woutT + (size_t)Dc * Dc;      // 1024*1024
  u16* Qb = wgateT + (size_t)Dc * Dc;         // 32*2048*64
  u16* Kb = Qb + (size_t)Bc * Hc * Sc * 64;
  u16* VbT = Kb + (size_t)Bc * Hc * Sc * 64;
  u16* ctxb = VbT + (size_t)Bc * Hc * Sc * 64;  // 4096*1024  (total 50 MB)

  ln_kernel<<<Mc, 256, 0, stream>>>(x, gamma, beta, xn);
  convertT<<<dim3(N3 / 32, Dc / 32), 256, 0, stream>>>(w_qkv, wqkvT, Dc, N3);
  convertT<<<dim3(Dc / 32, Dc / 32), 256, 0, stream>>>(w_out, woutT, Dc, Dc);
  convertT<<<dim3(Dc / 32, Dc / 32), 256, 0, stream>>>(w_gate, wgateT, Dc, Dc);
  gemm_qkv_kernel<<<dim3(N3 / 128, Mc / 128), 256, 0, stream>>>(
      xn, wqkvT, b_qkv, Qb, Kb, VbT);
  attn_kernel<<<512, 256, 0, stream>>>(Qb, Kb, VbT, ctxb);
  final_kernel<<<dim3(Dc / 64, Mc / 128), 256, 0, stream>>>(
      ctxb, xn, woutT, wgateT, b_out, b_gate, x, out);
}